// Round 1
// baseline (4630.036 us; speedup 1.0000x reference)
//
#include <hip/hip_runtime.h>
#include <hip/hip_bf16.h>
#include <cstddef>

// ---------------- constants ----------------
#define B_    32
#define S_    400
#define H_    512
#define E_    256
#define TM    63            // T-1 steps
#define V_    50000
#define VEXT_ 50050
#define KL    1280          // E + H + H  (x | ctx | h)

typedef __attribute__((ext_vector_type(8))) short  short8;   // 8 bf16
typedef __attribute__((ext_vector_type(4))) float  floatx4;

#define MFMA16(a,b,c) __builtin_amdgcn_mfma_f32_16x16x32_bf16((a),(b),(c),0,0,0)

// ---------------- workspace layout (float units) ----------------
constexpr size_t OFF_EP     = 0;          // ep_bf  [12800][512] bf16
constexpr size_t OFF_ENCBF  = 3276800;    // enc_bf [12800][512] bf16
constexpr size_t OFF_WENCT  = 6553600;    // WencT  [512][512] bf16
constexpr size_t OFF_WDECT  = 6684672;    // WdecT  [512][512] bf16
constexpr size_t OFF_WCAT   = 6815744;    // Wcat   [2048][1280] bf16
constexpr size_t OFF_WOUT   = 8126464;    // Wout_bf[50048][1024] bf16 (pad rows 0)
constexpr size_t OFF_ABF2   = 33751040;   // Abf2   [2048][1024] bf16 (pad rows 0)
constexpr size_t OFF_HSEQ   = 34799616;   // h_seq  [64][32][512] f32
constexpr size_t OFF_HBF    = 35848192;   // h_bf   [64][32][512] bf16
constexpr size_t OFF_CBUF   = 36372480;   // c      [32][512] f32
constexpr size_t OFF_CTXS   = 36388864;   // ctx    [63][32][512] f32
constexpr size_t OFF_ATTNS  = 37421056;   // attn   [63][32][400] f32
constexpr size_t OFF_COV    = 38227456;   // cov    [32][400] f32
constexpr size_t OFF_SCORES = 38240256;   // scores [32][400] f32
constexpr size_t OFF_DP     = 38253056;   // dp     [32][512] f32
constexpr size_t OFF_PGA    = 38269440;   // pgen acc [2016] (+pad)
constexpr size_t OFF_XDOT   = 38271488;   // x.w_emb_p [2016] (+pad)
constexpr size_t OFF_CLOSS  = 38273536;   // cov-loss acc
// total = 38273600 floats = 153.1 MB

// ---------------- helpers ----------------
__device__ __forceinline__ unsigned short f2bf(float f){
  unsigned int u = __float_as_uint(f);
  return (unsigned short)((u + 0x7FFFu + ((u >> 16) & 1u)) >> 16);
}
__device__ __forceinline__ float bf2f(unsigned short u){
  return __uint_as_float(((unsigned int)u) << 16);
}
__device__ __forceinline__ short8 cvt8(float4 a, float4 b){
  short8 o;
  o[0]=(short)f2bf(a.x); o[1]=(short)f2bf(a.y); o[2]=(short)f2bf(a.z); o[3]=(short)f2bf(a.w);
  o[4]=(short)f2bf(b.x); o[5]=(short)f2bf(b.y); o[6]=(short)f2bf(b.z); o[7]=(short)f2bf(b.w);
  return o;
}
__device__ __forceinline__ void ld8(const float* p, float* d){
  float4 a = *(const float4*)p, b = *(const float4*)(p+4);
  d[0]=a.x; d[1]=a.y; d[2]=a.z; d[3]=a.w; d[4]=b.x; d[5]=b.y; d[6]=b.z; d[7]=b.w;
}
__device__ __forceinline__ float wred(float v){
  #pragma unroll
  for (int o = 32; o; o >>= 1) v += __shfl_xor(v, o);
  return v;
}
__device__ __forceinline__ float wmax(float v){
  #pragma unroll
  for (int o = 32; o; o >>= 1) v = fmaxf(v, __shfl_xor(v, o));
  return v;
}
__device__ __forceinline__ float fast_tanh(float x){
  x = fminf(15.f, fmaxf(-15.f, x));
  float e = __expf(2.f * x);
  return (e - 1.f) * __builtin_amdgcn_rcpf(e + 1.f);
}
__device__ __forceinline__ float sigm(float x){
  return __builtin_amdgcn_rcpf(1.f + __expf(-x));
}

// ---------------- Phase A ----------------
__global__ __launch_bounds__(256) void k_init(const float* hidden, const float* cell, float* ws){
  int i = blockIdx.x * 256 + threadIdx.x;            // 0..16383
  if (i < 16384){
    float h = hidden[i];
    (ws + OFF_HSEQ)[i] = h;
    ((unsigned short*)(ws + OFF_HBF))[i] = f2bf(h);
    (ws + OFF_CBUF)[i] = cell[i];
  }
  if (i < 12800) (ws + OFF_COV)[i] = 0.f;
  if (i < 2048)  (ws + OFF_PGA)[i] = 0.f;
  if (i == 0)    (ws + OFF_CLOSS)[0] = 0.f;
}

__global__ __launch_bounds__(256) void k_xdot(const int* tgt, const float* emb, const float* wembp, float* ws){
  int w = threadIdx.x >> 6, lane = threadIdx.x & 63;
  int r = blockIdx.x * 4 + w; if (r >= 2016) return;
  int t = r >> 5, b = r & 31;
  const float* x = emb + (size_t)tgt[b * 64 + t] * E_;
  float4 xv = *(const float4*)(x + lane * 4);
  float4 wv = *(const float4*)(wembp + lane * 4);
  float s = xv.x*wv.x + xv.y*wv.y + xv.z*wv.z + xv.w*wv.w;
  s = wred(s);
  if (lane == 0) (ws + OFF_XDOT)[r] = s;
}

__global__ __launch_bounds__(256) void k_transpose_bf(const float* src, unsigned short* dst){
  int idx = blockIdx.x * 256 + threadIdx.x;   // 262144
  int n = idx >> 9, k = idx & 511;
  dst[idx] = f2bf(src[k * 512 + n]);
}

__global__ __launch_bounds__(256) void k_wcat(const float* Wih, const float* Whh, float* ws){
  int idx8 = (blockIdx.x * 256 + threadIdx.x) * 8;   // over 2048*1280
  int n = idx8 / 1280, k = idx8 - n * 1280;
  const float* src = (k < 768) ? (Wih + (size_t)n * 768 + k) : (Whh + (size_t)n * 512 + (k - 768));
  unsigned short* d = (unsigned short*)(ws + OFF_WCAT);
  *(short8*)(d + idx8) = cvt8(*(const float4*)src, *(const float4*)(src + 4));
}

__global__ __launch_bounds__(256) void k_wout(const float* Wout, float* ws){
  size_t idx8 = ((size_t)blockIdx.x * 256 + threadIdx.x) * 8;   // over 50048*1024
  size_t v = idx8 >> 10;
  unsigned short* d = (unsigned short*)(ws + OFF_WOUT);
  short8 o;
  if (v < (size_t)V_){
    const float* s = Wout + v * 1024 + (idx8 & 1023);
    o = cvt8(*(const float4*)s, *(const float4*)(s + 4));
  } else {
    #pragma unroll
    for (int i = 0; i < 8; i++) o[i] = 0;
  }
  *(short8*)(d + idx8) = o;
}

__global__ __launch_bounds__(256) void k_encbf(const float* enc, float* ws){
  size_t idx8 = ((size_t)blockIdx.x * 256 + threadIdx.x) * 8;   // over 12800*512
  const float* s = enc + idx8;
  unsigned short* d = (unsigned short*)(ws + OFF_ENCBF);
  *(short8*)(d + idx8) = cvt8(*(const float4*)s, *(const float4*)(s + 4));
}

// enc_proj GEMM: M=12800 (enc_bf), N=512 (WencT), K=512 -> ep_bf
__global__ __launch_bounds__(256, 2) void k_gemm_ep(float* ws){
  __shared__ unsigned short As[4096], Bs[4096];
  const unsigned short* A  = (const unsigned short*)(ws + OFF_ENCBF);
  const unsigned short* Bm = (const unsigned short*)(ws + OFF_WENCT);
  unsigned short* C = (unsigned short*)(ws + OFF_EP);
  int tid = threadIdx.x, lane = tid & 63, w = tid >> 6;
  int wm = w & 1, wn = w >> 1;
  floatx4 acc[4][4];
  #pragma unroll
  for (int i = 0; i < 4; i++)
    #pragma unroll
    for (int j = 0; j < 4; j++) acc[i][j] = (floatx4){0.f,0.f,0.f,0.f};
  for (int kt = 0; kt < 16; kt++){
    #pragma unroll
    for (int p = 0; p < 2; p++){
      int u = p * 256 + tid, m = u & 127, kb = u >> 7;
      int gk = kt * 32 + kb * 8;
      *(short8*)(As + (size_t)u * 8) = *(const short8*)(A  + ((size_t)(blockIdx.y * 128 + m)) * 512 + gk);
      *(short8*)(Bs + (size_t)u * 8) = *(const short8*)(Bm + ((size_t)(blockIdx.x * 128 + m)) * 512 + gk);
    }
    __syncthreads();
    int kbv = lane >> 4, lmv = lane & 15;
    short8 af[4], bfr[4];
    #pragma unroll
    for (int mf = 0; mf < 4; mf++) af[mf]  = *(const short8*)(As + (size_t)(kbv * 128 + wm * 64 + mf * 16 + lmv) * 8);
    #pragma unroll
    for (int nf = 0; nf < 4; nf++) bfr[nf] = *(const short8*)(Bs + (size_t)(kbv * 128 + wn * 64 + nf * 16 + lmv) * 8);
    #pragma unroll
    for (int mf = 0; mf < 4; mf++)
      #pragma unroll
      for (int nf = 0; nf < 4; nf++)
        acc[mf][nf] = MFMA16(af[mf], bfr[nf], acc[mf][nf]);
    __syncthreads();
  }
  int lm = lane & 15, q = lane >> 4;
  #pragma unroll
  for (int mf = 0; mf < 4; mf++)
    #pragma unroll
    for (int nf = 0; nf < 4; nf++)
      #pragma unroll
      for (int r = 0; r < 4; r++){
        int row = blockIdx.y * 128 + wm * 64 + mf * 16 + q * 4 + r;
        int col = blockIdx.x * 128 + wn * 64 + nf * 16 + lm;
        C[(size_t)row * 512 + col] = f2bf(acc[mf][nf][r]);
      }
}

// ---------------- Phase B (per step) ----------------
// dp = h_t @ W_dec   (M=32,N=512,K=512), grid 16
__global__ __launch_bounds__(256) void k_dp(float* ws, int t){
  const unsigned short* hbf = (const unsigned short*)(ws + OFF_HBF) + (size_t)t * 16384;
  const unsigned short* WdT = (const unsigned short*)(ws + OFF_WDECT);
  float* dp = ws + OFF_DP;
  __shared__ float pbuf[4][32][16];
  int tid = threadIdx.x, w = tid >> 6, lane = tid & 63;
  int nb = w >> 1, kh = w & 1;
  int n16 = blockIdx.x * 32 + nb * 16;
  int lm = lane & 15, kq = lane >> 4;
  floatx4 acc0 = (floatx4){0.f,0.f,0.f,0.f}, acc1 = (floatx4){0.f,0.f,0.f,0.f};
  #pragma unroll
  for (int ks = 0; ks < 8; ks++){
    int k = kh * 256 + ks * 32 + kq * 8;
    short8 a0 = *(const short8*)(hbf + (size_t)lm * 512 + k);
    short8 a1 = *(const short8*)(hbf + (size_t)(lm + 16) * 512 + k);
    short8 bb = *(const short8*)(WdT + (size_t)(n16 + lm) * 512 + k);
    acc0 = MFMA16(a0, bb, acc0);
    acc1 = MFMA16(a1, bb, acc1);
  }
  #pragma unroll
  for (int r = 0; r < 4; r++){
    pbuf[w][kq * 4 + r][lm]      = acc0[r];
    pbuf[w][16 + kq * 4 + r][lm] = acc1[r];
  }
  __syncthreads();
  for (int i = tid; i < 1024; i += 256){
    int c = i & 15, m = (i >> 4) & 31, nbb = i >> 9;
    dp[m * 512 + blockIdx.x * 32 + nbb * 16 + c] = pbuf[nbb * 2][m][c] + pbuf[nbb * 2 + 1][m][c];
  }
}

// scores[b][s] = v . tanh(ep + dp + cov*w_cov + b_att), masked
__global__ __launch_bounds__(256) void k_scores(float* ws, const float* wcov, const float* batt,
                                                const float* vatt, const int* lens, int t){
  int b = blockIdx.x >> 3, sc = blockIdx.x & 7;
  int tid = threadIdx.x, w = tid >> 6, lane = tid & 63;
  const unsigned short* epb = (const unsigned short*)(ws + OFF_EP) + (size_t)b * S_ * H_;
  const float* dp  = ws + OFF_DP + b * H_;
  const float* cov = ws + OFF_COV + b * S_;
  float* scores    = ws + OFF_SCORES + b * S_;
  int len = lens[b];
  float dpv[8], wcv[8], bav[8], vav[8];
  ld8(dp + lane * 8, dpv); ld8(wcov + lane * 8, wcv);
  ld8(batt + lane * 8, bav); ld8(vatt + lane * 8, vav);
  for (int s = sc * 50 + w; s < sc * 50 + 50; s += 4){
    if (s >= len){ if (lane == 0) scores[s] = -1e9f; continue; }
    float cv = cov[s];
    short8 e8 = *(const short8*)(epb + (size_t)s * H_ + lane * 8);
    float sum = 0.f;
    #pragma unroll
    for (int j = 0; j < 8; j++){
      float x = bf2f((unsigned short)e8[j]) + dpv[j] + cv * wcv[j] + bav[j];
      sum += fast_tanh(x) * vav[j];
    }
    sum = wred(sum);
    if (lane == 0) scores[s] = sum;
  }
}

// softmax -> attn, coverage update + loss, context chunk, pgen ctx-part
__global__ __launch_bounds__(256) void k_attn_ctx(float* ws, const float* wctx, int t){
  int b = blockIdx.x >> 3, hc = blockIdx.x & 7;
  int tid = threadIdx.x, w = tid >> 6, lane = tid & 63;
  __shared__ float attn_s[400];
  __shared__ float redA[4], redB[4];
  __shared__ float cpart[4][64];
  const float* scores = ws + OFF_SCORES + b * S_;
  float v0 = (tid < 400) ? scores[tid] : -1e30f;
  float v1 = (tid + 256 < 400) ? scores[tid + 256] : -1e30f;
  float lmax = wmax(fmaxf(v0, v1));
  if (lane == 0) redA[w] = lmax;
  __syncthreads();
  float M = fmaxf(fmaxf(redA[0], redA[1]), fmaxf(redA[2], redA[3]));
  float e0 = (tid < 400) ? __expf(v0 - M) : 0.f;
  float e1 = (tid + 256 < 400) ? __expf(v1 - M) : 0.f;
  if (tid < 400) attn_s[tid] = e0;
  if (tid + 256 < 400) attn_s[tid + 256] = e1;
  float ls = wred(e0 + e1);
  if (lane == 0) redB[w] = ls;
  __syncthreads();
  float SUM = redB[0] + redB[1] + redB[2] + redB[3];
  float rinv = __builtin_amdgcn_rcpf(SUM);
  // (a) this wg's 50-s slice: write attn, coverage loss, update cov
  float clp = 0.f;
  if (tid < 50){
    int s = hc * 50 + tid;
    float a  = attn_s[s] * rinv;
    float cv = (ws + OFF_COV)[b * S_ + s];
    clp = fminf(a, cv);
    (ws + OFF_COV)[b * S_ + s] = cv + a;
    (ws + OFF_ATTNS)[((size_t)t * 32 + b) * S_ + s] = a;
  }
  if (w == 0){
    clp = wred(clp);
    if (lane == 0) atomicAdd(ws + OFF_CLOSS, clp);
  }
  // (b) context chunk h in [hc*64, hc*64+64)
  const unsigned short* eb = (const unsigned short*)(ws + OFF_ENCBF)
                             + (size_t)b * S_ * H_ + hc * 64 + lane;
  float acc = 0.f;
  for (int s = w * 100; s < w * 100 + 100; s++)
    acc += attn_s[s] * bf2f(eb[(size_t)s * H_]);
  cpart[w][lane] = acc;
  __syncthreads();
  if (tid < 64){
    float c = (cpart[0][tid] + cpart[1][tid] + cpart[2][tid] + cpart[3][tid]) * rinv;
    (ws + OFF_CTXS)[((size_t)t * 32 + b) * H_ + hc * 64 + tid] = c;
    float pp = c * wctx[hc * 64 + tid];
    pp = wred(pp);
    if (tid == 0) atomicAdd(ws + OFF_PGA + t * 32 + b, pp);
  }
}

// LSTM: gates via MFMA, finalize h/c, pgen h-part.  grid 32 (h-chunks of 16)
__global__ __launch_bounds__(256) void k_lstm(float* ws, const int* tgt, const float* emb,
                                              const float* bih, const float* bhh,
                                              const float* wdecp, int t){
  __shared__ unsigned short Abf[32 * 648];     // K-chunk 640 (+8 pad)
  __shared__ float gbuf[4][32][16];
  __shared__ float pg[32][16];
  int tid = threadIdx.x, w = tid >> 6, lane = tid & 63;
  int j = blockIdx.x;
  int lm = lane & 15, kq = lane >> 4;
  int n = w * 512 + j * 16 + lm;               // gate row (wave = gate type)
  const unsigned short* Wc = (const unsigned short*)(ws + OFF_WCAT);
  floatx4 acc0 = (floatx4){0.f,0.f,0.f,0.f}, acc1 = (floatx4){0.f,0.f,0.f,0.f};
  for (int kc = 0; kc < 2; kc++){
    // stage A chunk: in = [x | ctx | h], rows = 32 batch
    for (int u = tid; u < 32 * 80; u += 256){
      int m = u / 80, ko = u - m * 80;
      int k = kc * 640 + ko * 8;
      const float* src;
      if (k < 256)      src = emb + (size_t)tgt[m * 64 + t] * E_ + k;
      else if (k < 768) src = ws + OFF_CTXS + ((size_t)t * 32 + m) * H_ + (k - 256);
      else              src = ws + OFF_HSEQ + (size_t)t * 16384 + m * H_ + (k - 768);
      *(short8*)(Abf + m * 648 + ko * 8) = cvt8(*(const float4*)src, *(const float4*)(src + 4));
    }
    __syncthreads();
    for (int ksl = 0; ksl < 20; ksl++){
      int kl = ksl * 32 + kq * 8;
      int k  = kc * 640 + kl;
      short8 a0 = *(const short8*)(Abf + lm * 648 + kl);
      short8 a1 = *(const short8*)(Abf + (lm + 16) * 648 + kl);
      short8 bb = *(const short8*)(Wc + (size_t)n * KL + k);
      acc0 = MFMA16(a0, bb, acc0);
      acc1 = MFMA16(a1, bb, acc1);
    }
    __syncthreads();
  }
  #pragma unroll
  for (int r = 0; r < 4; r++){
    gbuf[w][kq * 4 + r][lm]      = acc0[r];
    gbuf[w][16 + kq * 4 + r][lm] = acc1[r];
  }
  __syncthreads();
  float hnp[2]; int mA[2], hA[2];
  #pragma unroll
  for (int it = 0; it < 2; it++){
    int idx = tid + it * 256;
    int m = idx >> 4, hh = idx & 15;
    mA[it] = m; hA[it] = hh;
    int hg = j * 16 + hh;
    float gi = gbuf[0][m][hh] + bih[hg]        + bhh[hg];
    float gf = gbuf[1][m][hh] + bih[512 + hg]  + bhh[512 + hg];
    float gg = gbuf[2][m][hh] + bih[1024 + hg] + bhh[1024 + hg];
    float go = gbuf[3][m][hh] + bih[1536 + hg] + bhh[1536 + hg];
    float co = (ws + OFF_CBUF)[m * H_ + hg];
    float cn = sigm(gf) * co + sigm(gi) * fast_tanh(gg);
    float h1 = sigm(go) * fast_tanh(cn);
    (ws + OFF_CBUF)[m * H_ + hg] = cn;
    (ws + OFF_HSEQ)[(size_t)(t + 1) * 16384 + m * H_ + hg] = h1;
    ((unsigned short*)(ws + OFF_HBF))[(size_t)(t + 1) * 16384 + m * H_ + hg] = f2bf(h1);
    hnp[it] = h1 * wdecp[hg];
  }
  pg[mA[0]][hA[0]] = hnp[0];
  pg[mA[1]][hA[1]] = hnp[1];
  __syncthreads();
  if (tid < 32){
    float s = 0.f;
    #pragma unroll
    for (int q = 0; q < 16; q++) s += pg[tid][q];
    atomicAdd(ws + OFF_PGA + t * 32 + tid, s);
  }
}

// ---------------- Phase C ----------------
__global__ __launch_bounds__(256) void k_abf2(float* ws){
  int idx8 = (blockIdx.x * 256 + threadIdx.x) * 8;   // over 2048*1024
  int r = idx8 >> 10, k = idx8 & 1023;
  unsigned short* dst = (unsigned short*)(ws + OFF_ABF2);
  short8 o;
  if (r < 2016){
    int t = r >> 5, b = r & 31;
    const float* src = (k < 512)
      ? ws + OFF_HSEQ + (size_t)(t + 1) * 16384 + b * H_ + k
      : ws + OFF_CTXS + ((size_t)t * 32 + b) * H_ + (k - 512);
    o = cvt8(*(const float4*)src, *(const float4*)(src + 4));
  } else {
    #pragma unroll
    for (int i = 0; i < 8; i++) o[i] = 0;
  }
  *(short8*)(dst + idx8) = o;
}

// logits GEMM: M=2048, N=50048, K=1024; writes f32 logits into d_out rows
__global__ __launch_bounds__(256, 2) void k_gemm_out(float* ws, const float* bout, float* out){
  __shared__ unsigned short As[4096], Bs[4096];
  const unsigned short* A  = (const unsigned short*)(ws + OFF_ABF2);
  const unsigned short* Bm = (const unsigned short*)(ws + OFF_WOUT);
  int tid = threadIdx.x, lane = tid & 63, w = tid >> 6;
  int wm = w & 1, wn = w >> 1;
  floatx4 acc[4][4];
  #pragma unroll
  for (int i = 0; i < 4; i++)
    #pragma unroll
    for (int j = 0; j < 4; j++) acc[i][j] = (floatx4){0.f,0.f,0.f,0.f};
  for (int kt = 0; kt < 32; kt++){
    #pragma unroll
    for (int p = 0; p < 2; p++){
      int u = p * 256 + tid, m = u & 127, kb = u >> 7;
      int gk = kt * 32 + kb * 8;
      *(short8*)(As + (size_t)u * 8) = *(const short8*)(A  + ((size_t)(blockIdx.y * 128 + m)) * 1024 + gk);
      *(short8*)(Bs + (size_t)u * 8) = *(const short8*)(Bm + ((size_t)(blockIdx.x * 128 + m)) * 1024 + gk);
    }
    __syncthreads();
    int kbv = lane >> 4, lmv = lane & 15;
    short8 af[4], bfr[4];
    #pragma unroll
    for (int mf = 0; mf < 4; mf++) af[mf]  = *(const short8*)(As + (size_t)(kbv * 128 + wm * 64 + mf * 16 + lmv) * 8);
    #pragma unroll
    for (int nf = 0; nf < 4; nf++) bfr[nf] = *(const short8*)(Bs + (size_t)(kbv * 128 + wn * 64 + nf * 16 + lmv) * 8);
    #pragma unroll
    for (int mf = 0; mf < 4; mf++)
      #pragma unroll
      for (int nf = 0; nf < 4; nf++)
        acc[mf][nf] = MFMA16(af[mf], bfr[nf], acc[mf][nf]);
    __syncthreads();
  }
  int lm = lane & 15, q = lane >> 4;
  #pragma unroll
  for (int mf = 0; mf < 4; mf++)
    #pragma unroll
    for (int nf = 0; nf < 4; nf++)
      #pragma unroll
      for (int r = 0; r < 4; r++){
        int row = blockIdx.y * 128 + wm * 64 + mf * 16 + q * 4 + r;
        int col = blockIdx.x * 128 + wn * 64 + nf * 16 + lm;
        if (row < 2016 && col < V_){
          int t = row >> 5, b = row & 31;
          out[(size_t)(b * TM + t) * VEXT_ + col] = acc[mf][nf][r] + bout[col];
        }
      }
}

// per-row softmax + pgen scale + OOV-tail zero (in place on d_out)
__global__ __launch_bounds__(256) void k_softmax(float* out, float* ws, const float* bpgen){
  int r = blockIdx.x;                 // 0..2015
  int t = r >> 5, b = r & 31;
  float* row = out + (size_t)(b * TM + t) * VEXT_;
  int tid = threadIdx.x, w = tid >> 6, lane = tid & 63;
  __shared__ float redA[4], redB[4];
  float lmax = -1e30f;
  for (int v = tid * 2; v < V_; v += 512){
    float2 u = *(const float2*)(row + v);
    lmax = fmaxf(lmax, fmaxf(u.x, u.y));
  }
  lmax = wmax(lmax);
  if (lane == 0) redA[w] = lmax;
  __syncthreads();
  float M = fmaxf(fmaxf(redA[0], redA[1]), fmaxf(redA[2], redA[3]));
  float ls = 0.f;
  for (int v = tid * 2; v < V_; v += 512){
    float2 u = *(const float2*)(row + v);
    ls += __expf(u.x - M) + __expf(u.y - M);
  }
  ls = wred(ls);
  if (lane == 0) redB[w] = ls;
  __syncthreads();
  float SUM = redB[0] + redB[1] + redB[2] + redB[3];
  float pgen = sigm((ws + OFF_PGA)[r] + (ws + OFF_XDOT)[r] + bpgen[0]);
  float scale = pgen * __builtin_amdgcn_rcpf(SUM);
  for (int v = tid * 2; v < V_; v += 512){
    float2 u = *(const float2*)(row + v);
    u.x = __expf(u.x - M) * scale;
    u.y = __expf(u.y - M) * scale;
    *(float2*)(row + v) = u;
  }
  if (tid < 25) *(float2*)(row + V_ + tid * 2) = make_float2(0.f, 0.f);
}

// pointer scatter: out[row][oov_map[b][s]] += (1-pgen)*attn
__global__ __launch_bounds__(256) void k_scatter(float* out, float* ws, const int* oov,
                                                 const int* lens, const float* bpgen){
  int r = blockIdx.x;
  int t = r >> 5, b = r & 31;
  float pgen = sigm((ws + OFF_PGA)[r] + (ws + OFF_XDOT)[r] + bpgen[0]);
  float om = 1.f - pgen;
  float* row = out + (size_t)(b * TM + t) * VEXT_;
  const float* at = ws + OFF_ATTNS + (size_t)r * S_;
  const int* mp = oov + b * S_;
  int len = lens[b];
  for (int s = threadIdx.x; s < len; s += 256)
    atomicAdd(row + mp[s], om * at[s]);
}

__global__ __launch_bounds__(256) void k_final(float* out, const float* ws){
  int i = blockIdx.x * 256 + threadIdx.x;
  const size_t Oh = (size_t)B_ * TM * VEXT_;
  if (i < 16384){
    out[Oh + i]         = (ws + OFF_HSEQ)[(size_t)63 * 16384 + i];
    out[Oh + 16384 + i] = (ws + OFF_CBUF)[i];
  }
  if (i == 0) out[Oh + 32768] = (ws + OFF_CLOSS)[0] * (1.f / 2016.f);
}

// ---------------- launch ----------------
extern "C" void kernel_launch(void* const* d_in, const int* in_sizes, int n_in,
                              void* d_out, int out_size, void* d_ws, size_t ws_size,
                              hipStream_t stream){
  const int*   tgt    = (const int*)  d_in[0];
  const float* hidden = (const float*)d_in[1];
  const float* cell   = (const float*)d_in[2];
  const float* enc    = (const float*)d_in[3];
  const int*   lens   = (const int*)  d_in[4];
  const int*   oov    = (const int*)  d_in[5];
  const float* emb    = (const float*)d_in[6];
  const float* Wenc   = (const float*)d_in[7];
  const float* Wdec   = (const float*)d_in[8];
  const float* wcov   = (const float*)d_in[9];
  const float* vatt   = (const float*)d_in[10];
  const float* batt   = (const float*)d_in[11];
  const float* Wih    = (const float*)d_in[12];
  const float* Whh    = (const float*)d_in[13];
  const float* bih    = (const float*)d_in[14];
  const float* bhh    = (const float*)d_in[15];
  const float* Wout   = (const float*)d_in[16];
  const float* bout   = (const float*)d_in[17];
  const float* wctx   = (const float*)d_in[18];
  const float* wdecp  = (const float*)d_in[19];
  const float* wembp  = (const float*)d_in[20];
  const float* bpgen  = (const float*)d_in[21];
  float* out = (float*)d_out;
  float* ws  = (float*)d_ws;

  // Phase A
  k_init        <<<64,    256, 0, stream>>>(hidden, cell, ws);
  k_xdot        <<<504,   256, 0, stream>>>(tgt, emb, wembp, ws);
  k_transpose_bf<<<1024,  256, 0, stream>>>(Wenc, (unsigned short*)(ws + OFF_WENCT));
  k_transpose_bf<<<1024,  256, 0, stream>>>(Wdec, (unsigned short*)(ws + OFF_WDECT));
  k_wcat        <<<1280,  256, 0, stream>>>(Wih, Whh, ws);
  k_wout        <<<25024, 256, 0, stream>>>(Wout, ws);
  k_encbf       <<<3200,  256, 0, stream>>>(enc, ws);
  k_gemm_ep     <<<dim3(4, 100), 256, 0, stream>>>(ws);

  // Phase B: 63 sequential decode steps
  for (int t = 0; t < TM; t++){
    k_dp       <<<16,  256, 0, stream>>>(ws, t);
    k_scores   <<<256, 256, 0, stream>>>(ws, wcov, batt, vatt, lens, t);
    k_attn_ctx <<<256, 256, 0, stream>>>(ws, wctx, t);
    k_lstm     <<<32,  256, 0, stream>>>(ws, tgt, emb, bih, bhh, wdecp, t);
  }

  // Phase C: vocab distribution for all (t,b) at once
  k_abf2     <<<1024, 256, 0, stream>>>(ws);
  k_gemm_out <<<dim3(391, 16), 256, 0, stream>>>(ws, bout, out);
  k_softmax  <<<2016, 256, 0, stream>>>(out, ws, bpgen);
  k_scatter  <<<2016, 256, 0, stream>>>(out, ws, oov, lens, bpgen);
  k_final    <<<64,   256, 0, stream>>>(out, ws);
}